// Round 6
// baseline (1588.449 us; speedup 1.0000x reference)
//
#include <hip/hip_runtime.h>
#include <stdint.h>

// VectorQuantization: out[n] = codebook[argmax_k dot(x[n], codebook[k])]
// (argmax invariant to positive per-row scaling -> L2-normalize skipped,
//  and per-row max-norm int8 quantization is equally argmax-preserving)
//
// R9 = R8's i8 MFMA kernel with the LDS budget halved to DOUBLE OCCUPANCY:
// 2 rotating K-tile buffers (lookahead-1, 64 KiB) instead of 4 (128 KiB)
// -> 2 blocks/CU, 4 waves/SIMD. Rationale: R4/R5/R7/R8 all plateau at
// 35-43% of their MFMA ceiling at 1 block/CU -- the per-K-tile non-MFMA
// costs (12 ds_read burst, fold, acc init, barrier+vmcnt drain) are exposed
// because all 8 waves sync together with no co-resident block to fill the
// matrix pipe. With 2 independent blocks/CU the end-of-tile vmcnt(0) drain
// and fold tails of one block are covered by the other (m114-style implicit
// overlap). Stages are issued at the TOP of the K-tile body for max
// in-flight time.
//
// Race ledger (2 buffers, 1 barrier/kt): during kt, reads hit buf kt&1
// only. Stage of kt+1 (issued at top of kt) targets buf (kt+1)&1, whose
// last readers ran during kt-1, strictly before the kt-1 -> kt barrier.
// Before the end-of-kt barrier, vmcnt(0) drains this wave's kt+1 stages;
// the barrier globalizes -> kt+1's reads are safe. Tail: no stage at
// kt=G-1, skip the final wait+barrier (epilogue is register-only).
//
// R8 carried: per-row absmax x-quant + single global codebook absmax
// (both argmax-invariant), int-dot noise sigma ~276 int units with
// MARGIN_I=8000 (~29 sigma) + exact-fp64 recheck; zero-bank-conflict XOR
// chunk swizzle (SQ_LDS_BANK_CONFLICT == 0); gll16 staging; packed int
// top-2 keys (D<<5 | inverted 5-bit (coltile,j) code -> free lowest-index
// tie-break); ballot winner-lane recovery.
// New: x_quant + cb_absmax fused into one prep kernel (cbmax zeroed by a
// 4-byte hipMemsetAsync, graph-capture-safe) -> 4 kernel launches.

typedef int i32x4 __attribute__((ext_vector_type(4)));

#define M_ROWS 8192
#define DIM 512
#define DIMB 512                      /* bytes per i8 row */
#define K_CODES 16384
#define BM 256
#define BN 256
#define BKB 64                        /* K-tile depth in elements == bytes */
#define NSPLIT 16
#define NT ((K_CODES / NSPLIT) / BN)  /* 4 col-tiles per block */
#define KT_CT (DIM / BKB)             /* 8 K-tiles per col-tile */
#define G (NT * KT_CT)                /* 32 K-tiles per block */
#define MARGIN_I 8000.0f
#define INT_MIN_K (-2147483647 - 1)

typedef __attribute__((address_space(1))) uint32_t as1_u32;
typedef __attribute__((address_space(3))) uint32_t as3_u32;

__device__ __forceinline__ void gll16(const void* g, void* l) {
  // async global->LDS, 16B/lane; LDS dest = wave-uniform base + lane*16
  __builtin_amdgcn_global_load_lds((const as1_u32*)(uintptr_t)g,
                                   (as3_u32*)(uintptr_t)l, 16, 0, 0);
}

__device__ __forceinline__ float absmax4(float4 v) {
  return fmaxf(fmaxf(fabsf(v.x), fabsf(v.y)), fmaxf(fabsf(v.z), fabsf(v.w)));
}

__device__ __forceinline__ unsigned pack4(float a, float b, float c, float d, float inv) {
  const int q0 = __float2int_rn(a * inv), q1 = __float2int_rn(b * inv);
  const int q2 = __float2int_rn(c * inv), q3 = __float2int_rn(d * inv);
  return (unsigned)(q0 & 255) | ((unsigned)(q1 & 255) << 8) |
         ((unsigned)(q2 & 255) << 16) | ((unsigned)(q3 & 255) << 24);
}

// blocks [0,1024): one wave per x row -> per-row absmax quantize to i8.
// blocks [1024,2048): grid-stride absmax over codebook -> atomicMax(cbmax).
__global__ __launch_bounds__(512) void prep(
    const float* __restrict__ x, const float* __restrict__ cb,
    signed char* __restrict__ xq, unsigned* __restrict__ cbmax) {
  __shared__ float sm[8];
  if (blockIdx.x < 1024) {
    const int wv = threadIdx.x >> 6, lane = threadIdx.x & 63;
    const int row = blockIdx.x * 8 + wv;
    const float* xr = x + (size_t)row * DIM + lane * 8;
    const float4 v0 = *(const float4*)xr;
    const float4 v1 = *(const float4*)(xr + 4);
    float m = fmaxf(absmax4(v0), absmax4(v1));
#pragma unroll
    for (int d = 1; d < 64; d <<= 1) m = fmaxf(m, __shfl_xor(m, d));
    const float inv = m > 0.f ? 127.0f / m : 0.f;
    uint2 u;
    u.x = pack4(v0.x, v0.y, v0.z, v0.w, inv);
    u.y = pack4(v1.x, v1.y, v1.z, v1.w, inv);
    ((uint2*)(xq + (size_t)row * DIMB))[lane] = u;
  } else {
    const int n4 = K_CODES * DIM / 4;
    float m = 0.f;
    for (int i = (blockIdx.x - 1024) * 512 + threadIdx.x; i < n4; i += 512 * 1024)
      m = fmaxf(m, absmax4(((const float4*)cb)[i]));
#pragma unroll
    for (int d = 1; d < 64; d <<= 1) m = fmaxf(m, __shfl_xor(m, d));
    if ((threadIdx.x & 63) == 0) sm[threadIdx.x >> 6] = m;
    __syncthreads();
    if (threadIdx.x == 0) {
#pragma unroll
      for (int i = 1; i < 8; ++i) m = fmaxf(m, sm[i]);
      atomicMax((int*)cbmax, __float_as_int(m));  // positive floats: bit-monotone
    }
  }
}

__global__ void cb_quant(const float* __restrict__ cb, signed char* __restrict__ cq,
                         const unsigned* __restrict__ cbmax) {
  const float mx = __int_as_float((int)*cbmax);
  const float inv = mx > 0.f ? 127.0f / mx : 0.f;
  const size_t t = (size_t)blockIdx.x * 256 + threadIdx.x;  // 8 elems/thread
  const float* src = cb + t * 8;
  const float4 v0 = *(const float4*)src;
  const float4 v1 = *(const float4*)(src + 4);
  uint2 u;
  u.x = pack4(v0.x, v0.y, v0.z, v0.w, inv);
  u.y = pack4(v1.x, v1.y, v1.z, v1.w, inv);
  ((uint2*)cq)[t] = u;
}

__global__ __launch_bounds__(512, 4) void vq_argmax(
    const signed char* __restrict__ xq, const signed char* __restrict__ cq,
    float* __restrict__ pv, int* __restrict__ pi) {
  // 2 rotating single-K-tile buffers x {A,B} x (256 rows x 64B) = 64 KiB
  // -> 2 blocks/CU resident (the whole point of R9)
  __shared__ signed char lds[2][2][BM * BKB];

  const int tid = threadIdx.x;
  const int lane = tid & 63;
  const int w = tid >> 6;
  const int wm = w >> 1, wn = w & 1;       // 4M x 2N wave grid
  const int l15 = lane & 15, quad = lane >> 4;
  const int row0 = blockIdx.x * BM;
  const int split = blockIdx.y;
  // swizzled 16B-chunk byte offset for this lane's fragment reads
  const int kq = ((quad ^ ((l15 >> 1) & 3)) << 4);
  const int aoff = (wm * 64 + l15) * BKB + kq;
  const int boff = (wn * 128 + l15) * BKB + kq;

  // staging: slot s = r*512+tid holds logical chunk (row=s>>2, kc=(s&3)^((row>>1)&3))
  int eoff0, eoff1, doff0, doff1;
  {
    const int s1 = 512 + tid;
    const int r0 = tid >> 2, r1 = s1 >> 2;
    eoff0 = r0 * DIMB + (((tid & 3) ^ ((r0 >> 1) & 3)) << 4);
    eoff1 = r1 * DIMB + (((s1 & 3) ^ ((r1 >> 1) & 3)) << 4);
    doff0 = (tid & 448) << 4;
    doff1 = (512 + (tid & 448)) << 4;
  }
  const signed char* Asrc = xq + (size_t)row0 * DIMB;
  const signed char* Bsrc = cq + (size_t)split * (K_CODES / NSPLIT) * DIMB;

  auto stageA = [&](int t) {
    const signed char* g = Asrc + (t & 7) * BKB;
    signed char* l = &lds[t & 1][0][0];
    gll16(g + eoff0, l + doff0);
    gll16(g + eoff1, l + doff1);
  };
  auto stageB = [&](int t) {
    const signed char* g = Bsrc + (size_t)(t >> 3) * (BN * DIMB) + (t & 7) * BKB;
    signed char* l = &lds[t & 1][1][0];
    gll16(g + eoff0, l + doff0);
    gll16(g + eoff1, l + doff1);
  };

  // packed top-2 int keys per (i,r) row-slot: key = (D<<5) | icode_inv
  int K1[4][4], K2[4][4];
#pragma unroll
  for (int i = 0; i < 4; ++i)
#pragma unroll
    for (int r = 0; r < 4; ++r) { K1[i][r] = INT_MIN_K; K2[i][r] = INT_MIN_K; }

  i32x4 acc[4][8];

  auto fold = [&](int j0, int j1, int kt) {
    const int icb = 31 - (kt >> 3) * 8;   // icode_inv = icb - j
#pragma unroll
    for (int j = j0; j < j1; ++j) {
      const int xo = icb - j;
#pragma unroll
      for (int i = 0; i < 4; ++i)
#pragma unroll
        for (int r = 0; r < 4; ++r) {
          const int k = (int)(((unsigned)acc[i][j][r] << 5) | (unsigned)xo);
          const bool gt = k > K1[i][r];
          const int t2 = K2[i][r] > k ? K2[i][r] : k;
          K2[i][r] = gt ? K1[i][r] : t2;
          K1[i][r] = gt ? k : K1[i][r];
        }
    }
  };

  // prologue: stage K-tile 0, drain, sync
  stageA(0); stageB(0);
  asm volatile("s_waitcnt vmcnt(0)" ::: "memory");
  __builtin_amdgcn_s_barrier();
  asm volatile("" ::: "memory");

#pragma unroll 1
  for (int kt = 0; kt < G; ++kt) {
    const int bk = kt & 1;
    // stage kt+1 FIRST (max in-flight time before the end-of-tile drain);
    // targets the buffer last read during kt-1, pre-barrier -> safe
    if (kt + 1 < G) { stageA(kt + 1); stageB(kt + 1); }

    if ((kt & 7) == 0) {
#pragma unroll
      for (int i = 0; i < 4; ++i)
#pragma unroll
        for (int j = 0; j < 8; ++j) acc[i][j] = (i32x4){0, 0, 0, 0};
    }
    const signed char* Ab = &lds[bk][0][0];
    const signed char* Bb = &lds[bk][1][0];

    // all 12 fragment reads up front in need-order; counted lgkm lets the
    // later B reads complete under the first MFMA group
    i32x4 A_[4], B_[8];
#pragma unroll
    for (int i = 0; i < 4; ++i) A_[i] = *(const i32x4*)&Ab[aoff + i * (16 * BKB)];
#pragma unroll
    for (int j = 0; j < 8; ++j) B_[j] = *(const i32x4*)&Bb[boff + j * (16 * BKB)];

    __builtin_amdgcn_s_setprio(1);
#pragma unroll
    for (int j = 0; j < 4; ++j)
#pragma unroll
      for (int i = 0; i < 4; ++i)
        acc[i][j] = __builtin_amdgcn_mfma_i32_16x16x64_i8(A_[i], B_[j], acc[i][j], 0, 0, 0);
    __builtin_amdgcn_s_setprio(0);
    if ((kt & 7) == 7) fold(0, 4, kt);   // VALU half-fold under next MFMA group
    __builtin_amdgcn_s_setprio(1);
#pragma unroll
    for (int j = 4; j < 8; ++j)
#pragma unroll
      for (int i = 0; i < 4; ++i)
        acc[i][j] = __builtin_amdgcn_mfma_i32_16x16x64_i8(A_[i], B_[j], acc[i][j], 0, 0, 0);
    __builtin_amdgcn_s_setprio(0);
    if ((kt & 7) == 7) fold(4, 8, kt);

    // drain this wave's kt+1 stages, then globalize; the stall is covered by
    // the co-resident block (independent barrier domain)
    if (kt + 1 < G) {
      asm volatile("s_waitcnt vmcnt(0)" ::: "memory");
      __builtin_amdgcn_s_barrier();
      asm volatile("" ::: "memory");
    }
  }

  // butterfly-merge top-2 across the 16 column-lanes of each quad, recover
  // winner lane via ballot (first set bit = lowest l15 = lowest index on tie)
  const int nb = split * (K_CODES / NSPLIT);
#pragma unroll
  for (int i = 0; i < 4; ++i)
#pragma unroll
    for (int r = 0; r < 4; ++r) {
      const int p1 = K1[i][r], p2 = K2[i][r];
      int a1 = p1, a2 = p2;
#pragma unroll
      for (int d = 1; d < 16; d <<= 1) {
        const int b1 = __shfl_xor(a1, d);
        const int b2 = __shfl_xor(a2, d);
        const int hi = a1 > b1 ? a1 : b1;
        const int lo = a1 > b1 ? b1 : a1;
        const int mx = a2 > b2 ? a2 : b2;
        a1 = hi;
        a2 = lo > mx ? lo : mx;
      }
      const unsigned long long bl1 = __ballot(p1 == a1);
      const int s1 = __ffsll((unsigned long long)((bl1 >> (quad * 16)) & 0xFFFFull)) - 1;
      const unsigned long long bl2 = __ballot((p2 == a2) || (p1 == a2 && l15 != s1));
      const int s2 = __ffsll((unsigned long long)((bl2 >> (quad * 16)) & 0xFFFFull)) - 1;
      if (l15 == 0) {
        const int code1 = 31 - (a1 & 31);
        const int code2 = 31 - (a2 & 31);
        const int col1 = nb + (code1 >> 3) * BN + wn * 128 + (code1 & 7) * 16 + s1;
        const int col2 = nb + (code2 >> 3) * BN + wn * 128 + (code2 & 7) * 16 + s2;
        const int rl = wm * 64 + i * 16 + quad * 4 + r;
        const size_t o = (size_t)(row0 + rl) * 64 + (size_t)(split * 4 + wn * 2);
        pv[o] = (float)(a1 >> 5); pi[o] = col1;       // D in int units; margin
        pv[o + 1] = (float)(a2 >> 5); pi[o + 1] = col2;  // test is relative/row
      }
    }
}

__global__ void recheck_gather(const float* __restrict__ pv, const int* __restrict__ pi,
                               const float* __restrict__ x, const float* __restrict__ cb,
                               float* __restrict__ out) {
  const int row = blockIdx.x;
  const int lane = threadIdx.x;   // 64 candidates = 16 splits x 2 halves x top-2
  float v = pv[(size_t)row * 64 + lane];
  int ci = pi[(size_t)row * 64 + lane];

  // wave max with lowest-index tie-break
  float m1 = v; int mi1 = ci;
#pragma unroll
  for (int d = 1; d < 64; d <<= 1) {
    float ov = __shfl_xor(m1, d);
    int oi = __shfl_xor(mi1, d);
    if (ov > m1 || (ov == m1 && oi < mi1)) { m1 = ov; mi1 = oi; }
  }

  const bool flag = (v >= m1 - MARGIN_I);
  const unsigned long long mask = __ballot(flag);
  int winner;
  if (__popcll(mask) == 1) {
    winner = mi1;   // approx winner is ~29-sigma clear of every other candidate
  } else {
    // exact fp64 dot from original fp32 inputs for each flagged candidate
    double e = -1.0e300;
    if (flag) {
      const float* xr = x + (size_t)row * DIM;
      const float* cr = cb + (size_t)ci * DIM;
      double s = 0.0;
#pragma unroll 4
      for (int t = 0; t < DIM; t += 4) {
        const float4 a = *(const float4*)(xr + t);
        const float4 b = *(const float4*)(cr + t);
        s += (double)a.x * b.x + (double)a.y * b.y + (double)a.z * b.z + (double)a.w * b.w;
      }
      e = s;
    }
    int ei = flag ? ci : 0x7fffffff;
#pragma unroll
    for (int d = 1; d < 64; d <<= 1) {
      double oe = __shfl_xor(e, d);
      int oi = __shfl_xor(ei, d);
      if (oe > e || (oe == e && oi < ei)) { e = oe; ei = oi; }
    }
    winner = ei;
  }

  const float4* src = (const float4*)(cb + (size_t)winner * DIM);
  float4* dst = (float4*)(out + (size_t)row * DIM);
  dst[lane] = src[lane];         // 512 f32 = 128 float4, 64 lanes x 2
  dst[lane + 64] = src[lane + 64];
}

extern "C" void kernel_launch(void* const* d_in, const int* in_sizes, int n_in,
                              void* d_out, int out_size, void* d_ws, size_t ws_size,
                              hipStream_t stream) {
  const float* x = (const float*)d_in[0];
  const float* cb = (const float*)d_in[1];
  float* out = (float*)d_out;

  // ws layout: xq(4MB) cq(8MB) pv(2MB) pi(2MB) cbmax(4B)
  signed char* xq = (signed char*)d_ws;
  signed char* cq = xq + (size_t)M_ROWS * DIMB;
  float* pv = (float*)(cq + (size_t)K_CODES * DIMB);
  int* pi = (int*)(pv + (size_t)M_ROWS * 64);
  unsigned* cbmax = (unsigned*)(pi + (size_t)M_ROWS * 64);

  hipMemsetAsync(cbmax, 0, sizeof(unsigned), stream);  // capture-safe async memset
  prep<<<2048, 512, 0, stream>>>(x, cb, xq, cbmax);
  cb_quant<<<K_CODES * DIM / 8 / 256, 256, 0, stream>>>(cb, cq, cbmax);
  vq_argmax<<<dim3(M_ROWS / BM, NSPLIT), 512, 0, stream>>>(xq, cq, pv, pi);
  recheck_gather<<<M_ROWS, 64, 0, stream>>>(pv, pi, x, cb, out);
}

// Round 7
// 229.880 us; speedup vs baseline: 6.9099x; 6.9099x over previous
//
#include <hip/hip_runtime.h>
#include <stdint.h>

// VectorQuantization: out[n] = codebook[argmax_k dot(x[n], codebook[k])]
// (argmax invariant to positive per-row scaling -> L2-normalize skipped,
//  and per-row max-norm int8 quantization is equally argmax-preserving)
//
// R10 = R9's 2-buffer/double-occupancy i8 kernel with the launch-bounds bug
// fixed. R9's __launch_bounds__(512,4) made the allocator cap at 64 VGPR
// (2048-pool/32-waves -- the 2nd arg empirically acts as min BLOCKS/CU on
// this toolchain) -> massive scratch spill (WRITE 4.9 GB, MfmaUtil 1.9%).
// Back to (512,2): R8 measured 116 VGPR under this bound, and 116 <= 128
// means 2 blocks/CU co-schedule from the VGPR side anyway; LDS 64 KiB x 2
// = 128 <= 160 KiB. Residency comes from resource shapes, not a forced cap.
//
// Structure (unchanged from R9): 2 rotating K-tile buffers (lookahead-1,
// 64 KiB), stage kt+1 at TOP of kt body, all 12 fragment ds_read_b128 up
// front in need-order, 32 MFMA in two setprio(1) groups with the col-tile
// fold halves interleaved, one vmcnt(0)+barrier per K-tile -- the drain is
// covered by the co-resident block (independent barrier domain, m114-style
// implicit overlap).
//
// Race ledger (2 buffers, 1 barrier/kt): during kt, reads hit buf kt&1
// only. Stage of kt+1 (issued at top of kt) targets buf (kt+1)&1, whose
// last readers ran during kt-1, strictly before the kt-1 -> kt barrier.
// Before the end-of-kt barrier, vmcnt(0) drains this wave's kt+1 stages;
// the barrier globalizes -> kt+1's reads are safe. Tail: no stage at
// kt=G-1, skip the final wait+barrier (epilogue is register-only).
//
// Carried: per-row absmax x-quant + single global codebook absmax (both
// argmax-invariant), int-dot noise sigma ~276 int units, MARGIN_I=8000
// (~29 sigma) + exact-fp64 recheck; zero-bank-conflict XOR chunk swizzle
// (SQ_LDS_BANK_CONFLICT == 0); gll16 staging; packed int top-2 keys
// (D<<5 | inverted 5-bit (coltile,j) code -> free lowest-index tie-break);
// ballot winner-lane recovery; fused prep kernel; 4 launches +
// capture-safe hipMemsetAsync.

typedef int i32x4 __attribute__((ext_vector_type(4)));

#define M_ROWS 8192
#define DIM 512
#define DIMB 512                      /* bytes per i8 row */
#define K_CODES 16384
#define BM 256
#define BN 256
#define BKB 64                        /* K-tile depth in elements == bytes */
#define NSPLIT 16
#define NT ((K_CODES / NSPLIT) / BN)  /* 4 col-tiles per block */
#define KT_CT (DIM / BKB)             /* 8 K-tiles per col-tile */
#define G (NT * KT_CT)                /* 32 K-tiles per block */
#define MARGIN_I 8000.0f
#define INT_MIN_K (-2147483647 - 1)

typedef __attribute__((address_space(1))) uint32_t as1_u32;
typedef __attribute__((address_space(3))) uint32_t as3_u32;

__device__ __forceinline__ void gll16(const void* g, void* l) {
  // async global->LDS, 16B/lane; LDS dest = wave-uniform base + lane*16
  __builtin_amdgcn_global_load_lds((const as1_u32*)(uintptr_t)g,
                                   (as3_u32*)(uintptr_t)l, 16, 0, 0);
}

__device__ __forceinline__ float absmax4(float4 v) {
  return fmaxf(fmaxf(fabsf(v.x), fabsf(v.y)), fmaxf(fabsf(v.z), fabsf(v.w)));
}

__device__ __forceinline__ unsigned pack4(float a, float b, float c, float d, float inv) {
  const int q0 = __float2int_rn(a * inv), q1 = __float2int_rn(b * inv);
  const int q2 = __float2int_rn(c * inv), q3 = __float2int_rn(d * inv);
  return (unsigned)(q0 & 255) | ((unsigned)(q1 & 255) << 8) |
         ((unsigned)(q2 & 255) << 16) | ((unsigned)(q3 & 255) << 24);
}

// blocks [0,1024): one wave per x row -> per-row absmax quantize to i8.
// blocks [1024,2048): grid-stride absmax over codebook -> atomicMax(cbmax).
__global__ __launch_bounds__(512) void prep(
    const float* __restrict__ x, const float* __restrict__ cb,
    signed char* __restrict__ xq, unsigned* __restrict__ cbmax) {
  __shared__ float sm[8];
  if (blockIdx.x < 1024) {
    const int wv = threadIdx.x >> 6, lane = threadIdx.x & 63;
    const int row = blockIdx.x * 8 + wv;
    const float* xr = x + (size_t)row * DIM + lane * 8;
    const float4 v0 = *(const float4*)xr;
    const float4 v1 = *(const float4*)(xr + 4);
    float m = fmaxf(absmax4(v0), absmax4(v1));
#pragma unroll
    for (int d = 1; d < 64; d <<= 1) m = fmaxf(m, __shfl_xor(m, d));
    const float inv = m > 0.f ? 127.0f / m : 0.f;
    uint2 u;
    u.x = pack4(v0.x, v0.y, v0.z, v0.w, inv);
    u.y = pack4(v1.x, v1.y, v1.z, v1.w, inv);
    ((uint2*)(xq + (size_t)row * DIMB))[lane] = u;
  } else {
    const int n4 = K_CODES * DIM / 4;
    float m = 0.f;
    for (int i = (blockIdx.x - 1024) * 512 + threadIdx.x; i < n4; i += 512 * 1024)
      m = fmaxf(m, absmax4(((const float4*)cb)[i]));
#pragma unroll
    for (int d = 1; d < 64; d <<= 1) m = fmaxf(m, __shfl_xor(m, d));
    if ((threadIdx.x & 63) == 0) sm[threadIdx.x >> 6] = m;
    __syncthreads();
    if (threadIdx.x == 0) {
#pragma unroll
      for (int i = 1; i < 8; ++i) m = fmaxf(m, sm[i]);
      atomicMax((int*)cbmax, __float_as_int(m));  // positive floats: bit-monotone
    }
  }
}

__global__ void cb_quant(const float* __restrict__ cb, signed char* __restrict__ cq,
                         const unsigned* __restrict__ cbmax) {
  const float mx = __int_as_float((int)*cbmax);
  const float inv = mx > 0.f ? 127.0f / mx : 0.f;
  const size_t t = (size_t)blockIdx.x * 256 + threadIdx.x;  // 8 elems/thread
  const float* src = cb + t * 8;
  const float4 v0 = *(const float4*)src;
  const float4 v1 = *(const float4*)(src + 4);
  uint2 u;
  u.x = pack4(v0.x, v0.y, v0.z, v0.w, inv);
  u.y = pack4(v1.x, v1.y, v1.z, v1.w, inv);
  ((uint2*)cq)[t] = u;
}

__global__ __launch_bounds__(512, 2) void vq_argmax(
    const signed char* __restrict__ xq, const signed char* __restrict__ cq,
    float* __restrict__ pv, int* __restrict__ pi) {
  // 2 rotating single-K-tile buffers x {A,B} x (256 rows x 64B) = 64 KiB
  // -> 2 blocks/CU resident via resource shapes (VGPR ~116 <= 128, LDS
  // 64x2 <= 160), NOT via a forced register cap (R9's mistake)
  __shared__ signed char lds[2][2][BM * BKB];

  const int tid = threadIdx.x;
  const int lane = tid & 63;
  const int w = tid >> 6;
  const int wm = w >> 1, wn = w & 1;       // 4M x 2N wave grid
  const int l15 = lane & 15, quad = lane >> 4;
  const int row0 = blockIdx.x * BM;
  const int split = blockIdx.y;
  // swizzled 16B-chunk byte offset for this lane's fragment reads
  const int kq = ((quad ^ ((l15 >> 1) & 3)) << 4);
  const int aoff = (wm * 64 + l15) * BKB + kq;
  const int boff = (wn * 128 + l15) * BKB + kq;

  // staging: slot s = r*512+tid holds logical chunk (row=s>>2, kc=(s&3)^((row>>1)&3))
  int eoff0, eoff1, doff0, doff1;
  {
    const int s1 = 512 + tid;
    const int r0 = tid >> 2, r1 = s1 >> 2;
    eoff0 = r0 * DIMB + (((tid & 3) ^ ((r0 >> 1) & 3)) << 4);
    eoff1 = r1 * DIMB + (((s1 & 3) ^ ((r1 >> 1) & 3)) << 4);
    doff0 = (tid & 448) << 4;
    doff1 = (512 + (tid & 448)) << 4;
  }
  const signed char* Asrc = xq + (size_t)row0 * DIMB;
  const signed char* Bsrc = cq + (size_t)split * (K_CODES / NSPLIT) * DIMB;

  auto stageA = [&](int t) {
    const signed char* g = Asrc + (t & 7) * BKB;
    signed char* l = &lds[t & 1][0][0];
    gll16(g + eoff0, l + doff0);
    gll16(g + eoff1, l + doff1);
  };
  auto stageB = [&](int t) {
    const signed char* g = Bsrc + (size_t)(t >> 3) * (BN * DIMB) + (t & 7) * BKB;
    signed char* l = &lds[t & 1][1][0];
    gll16(g + eoff0, l + doff0);
    gll16(g + eoff1, l + doff1);
  };

  // packed top-2 int keys per (i,r) row-slot: key = (D<<5) | icode_inv
  int K1[4][4], K2[4][4];
#pragma unroll
  for (int i = 0; i < 4; ++i)
#pragma unroll
    for (int r = 0; r < 4; ++r) { K1[i][r] = INT_MIN_K; K2[i][r] = INT_MIN_K; }

  i32x4 acc[4][8];

  auto fold = [&](int j0, int j1, int kt) {
    const int icb = 31 - (kt >> 3) * 8;   // icode_inv = icb - j
#pragma unroll
    for (int j = j0; j < j1; ++j) {
      const int xo = icb - j;
#pragma unroll
      for (int i = 0; i < 4; ++i)
#pragma unroll
        for (int r = 0; r < 4; ++r) {
          const int k = (int)(((unsigned)acc[i][j][r] << 5) | (unsigned)xo);
          const bool gt = k > K1[i][r];
          const int t2 = K2[i][r] > k ? K2[i][r] : k;
          K2[i][r] = gt ? K1[i][r] : t2;
          K1[i][r] = gt ? k : K1[i][r];
        }
    }
  };

  // prologue: stage K-tile 0, drain, sync
  stageA(0); stageB(0);
  asm volatile("s_waitcnt vmcnt(0)" ::: "memory");
  __builtin_amdgcn_s_barrier();
  asm volatile("" ::: "memory");

#pragma unroll 1
  for (int kt = 0; kt < G; ++kt) {
    const int bk = kt & 1;
    // stage kt+1 FIRST (max in-flight time before the end-of-tile drain);
    // targets the buffer last read during kt-1, pre-barrier -> safe
    if (kt + 1 < G) { stageA(kt + 1); stageB(kt + 1); }

    if ((kt & 7) == 0) {
#pragma unroll
      for (int i = 0; i < 4; ++i)
#pragma unroll
        for (int j = 0; j < 8; ++j) acc[i][j] = (i32x4){0, 0, 0, 0};
    }
    const signed char* Ab = &lds[bk][0][0];
    const signed char* Bb = &lds[bk][1][0];

    // all 12 fragment reads up front in need-order; counted lgkm lets the
    // later B reads complete under the first MFMA group
    i32x4 A_[4], B_[8];
#pragma unroll
    for (int i = 0; i < 4; ++i) A_[i] = *(const i32x4*)&Ab[aoff + i * (16 * BKB)];
#pragma unroll
    for (int j = 0; j < 8; ++j) B_[j] = *(const i32x4*)&Bb[boff + j * (16 * BKB)];

    __builtin_amdgcn_s_setprio(1);
#pragma unroll
    for (int j = 0; j < 4; ++j)
#pragma unroll
      for (int i = 0; i < 4; ++i)
        acc[i][j] = __builtin_amdgcn_mfma_i32_16x16x64_i8(A_[i], B_[j], acc[i][j], 0, 0, 0);
    __builtin_amdgcn_s_setprio(0);
    if ((kt & 7) == 7) fold(0, 4, kt);   // VALU half-fold under next MFMA group
    __builtin_amdgcn_s_setprio(1);
#pragma unroll
    for (int j = 4; j < 8; ++j)
#pragma unroll
      for (int i = 0; i < 4; ++i)
        acc[i][j] = __builtin_amdgcn_mfma_i32_16x16x64_i8(A_[i], B_[j], acc[i][j], 0, 0, 0);
    __builtin_amdgcn_s_setprio(0);
    if ((kt & 7) == 7) fold(4, 8, kt);

    // drain this wave's kt+1 stages, then globalize; the stall is covered by
    // the co-resident block (independent barrier domain)
    if (kt + 1 < G) {
      asm volatile("s_waitcnt vmcnt(0)" ::: "memory");
      __builtin_amdgcn_s_barrier();
      asm volatile("" ::: "memory");
    }
  }

  // butterfly-merge top-2 across the 16 column-lanes of each quad, recover
  // winner lane via ballot (first set bit = lowest l15 = lowest index on tie)
  const int nb = split * (K_CODES / NSPLIT);
#pragma unroll
  for (int i = 0; i < 4; ++i)
#pragma unroll
    for (int r = 0; r < 4; ++r) {
      const int p1 = K1[i][r], p2 = K2[i][r];
      int a1 = p1, a2 = p2;
#pragma unroll
      for (int d = 1; d < 16; d <<= 1) {
        const int b1 = __shfl_xor(a1, d);
        const int b2 = __shfl_xor(a2, d);
        const int hi = a1 > b1 ? a1 : b1;
        const int lo = a1 > b1 ? b1 : a1;
        const int mx = a2 > b2 ? a2 : b2;
        a1 = hi;
        a2 = lo > mx ? lo : mx;
      }
      const unsigned long long bl1 = __ballot(p1 == a1);
      const int s1 = __ffsll((unsigned long long)((bl1 >> (quad * 16)) & 0xFFFFull)) - 1;
      const unsigned long long bl2 = __ballot((p2 == a2) || (p1 == a2 && l15 != s1));
      const int s2 = __ffsll((unsigned long long)((bl2 >> (quad * 16)) & 0xFFFFull)) - 1;
      if (l15 == 0) {
        const int code1 = 31 - (a1 & 31);
        const int code2 = 31 - (a2 & 31);
        const int col1 = nb + (code1 >> 3) * BN + wn * 128 + (code1 & 7) * 16 + s1;
        const int col2 = nb + (code2 >> 3) * BN + wn * 128 + (code2 & 7) * 16 + s2;
        const int rl = wm * 64 + i * 16 + quad * 4 + r;
        const size_t o = (size_t)(row0 + rl) * 64 + (size_t)(split * 4 + wn * 2);
        pv[o] = (float)(a1 >> 5); pi[o] = col1;       // D in int units; margin
        pv[o + 1] = (float)(a2 >> 5); pi[o + 1] = col2;  // test is relative/row
      }
    }
}

__global__ void recheck_gather(const float* __restrict__ pv, const int* __restrict__ pi,
                               const float* __restrict__ x, const float* __restrict__ cb,
                               float* __restrict__ out) {
  const int row = blockIdx.x;
  const int lane = threadIdx.x;   // 64 candidates = 16 splits x 2 halves x top-2
  float v = pv[(size_t)row * 64 + lane];
  int ci = pi[(size_t)row * 64 + lane];

  // wave max with lowest-index tie-break
  float m1 = v; int mi1 = ci;
#pragma unroll
  for (int d = 1; d < 64; d <<= 1) {
    float ov = __shfl_xor(m1, d);
    int oi = __shfl_xor(mi1, d);
    if (ov > m1 || (ov == m1 && oi < mi1)) { m1 = ov; mi1 = oi; }
  }

  const bool flag = (v >= m1 - MARGIN_I);
  const unsigned long long mask = __ballot(flag);
  int winner;
  if (__popcll(mask) == 1) {
    winner = mi1;   // approx winner is ~29-sigma clear of every other candidate
  } else {
    // exact fp64 dot from original fp32 inputs for each flagged candidate
    double e = -1.0e300;
    if (flag) {
      const float* xr = x + (size_t)row * DIM;
      const float* cr = cb + (size_t)ci * DIM;
      double s = 0.0;
#pragma unroll 4
      for (int t = 0; t < DIM; t += 4) {
        const float4 a = *(const float4*)(xr + t);
        const float4 b = *(const float4*)(cr + t);
        s += (double)a.x * b.x + (double)a.y * b.y + (double)a.z * b.z + (double)a.w * b.w;
      }
      e = s;
    }
    int ei = flag ? ci : 0x7fffffff;
#pragma unroll
    for (int d = 1; d < 64; d <<= 1) {
      double oe = __shfl_xor(e, d);
      int oi = __shfl_xor(ei, d);
      if (oe > e || (oe == e && oi < ei)) { e = oe; ei = oi; }
    }
    winner = ei;
  }

  const float4* src = (const float4*)(cb + (size_t)winner * DIM);
  float4* dst = (float4*)(out + (size_t)row * DIM);
  dst[lane] = src[lane];         // 512 f32 = 128 float4, 64 lanes x 2
  dst[lane + 64] = src[lane + 64];
}

extern "C" void kernel_launch(void* const* d_in, const int* in_sizes, int n_in,
                              void* d_out, int out_size, void* d_ws, size_t ws_size,
                              hipStream_t stream) {
  const float* x = (const float*)d_in[0];
  const float* cb = (const float*)d_in[1];
  float* out = (float*)d_out;

  // ws layout: xq(4MB) cq(8MB) pv(2MB) pi(2MB) cbmax(4B)
  signed char* xq = (signed char*)d_ws;
  signed char* cq = xq + (size_t)M_ROWS * DIMB;
  float* pv = (float*)(cq + (size_t)K_CODES * DIMB);
  int* pi = (int*)(pv + (size_t)M_ROWS * 64);
  unsigned* cbmax = (unsigned*)(pi + (size_t)M_ROWS * 64);

  hipMemsetAsync(cbmax, 0, sizeof(unsigned), stream);  // capture-safe async memset
  prep<<<2048, 512, 0, stream>>>(x, cb, xq, cbmax);
  cb_quant<<<K_CODES * DIM / 8 / 256, 256, 0, stream>>>(cb, cq, cbmax);
  vq_argmax<<<dim3(M_ROWS / BM, NSPLIT), 512, 0, stream>>>(xq, cq, pv, pi);
  recheck_gather<<<M_ROWS, 64, 0, stream>>>(pv, pi, x, cb, out);
}